// Round 3
// baseline (3971.082 us; speedup 1.0000x reference)
//
#include <hip/hip_runtime.h>
#include <cfloat>

// Problem constants (fixed by setup_inputs)
#define BATCH 128
#define NP    16384
#define NC    4096
#define MPTS  (NP + NC)   // 20480
#define SOUT  2048
#define NTHR  1024
#define KPT   (MPTS / NTHR) // 20 points per thread
#define KPART (NP / NTHR)   // 16 of them come from `partial`

__device__ inline unsigned int shflxor32(unsigned int v, int mask) {
    return (unsigned int)__shfl_xor((int)v, mask, 64);
}
__device__ inline unsigned long long shflxor64(unsigned long long v, int mask) {
    unsigned int lo = (unsigned int)v;
    unsigned int hi = (unsigned int)(v >> 32);
    lo = shflxor32(lo, mask);
    hi = shflxor32(hi, mask);
    return ((unsigned long long)hi << 32) | (unsigned long long)lo;
}

// One block per batch. Each thread owns KPT points (interleaved: m = k*NTHR + t)
// and their running min_d, all in registers. Winner coords are written directly
// to the output (gather fused).
__global__ __launch_bounds__(NTHR) void fps_kernel(
    const float* __restrict__ partial,   // [B, NP, 3]
    const float* __restrict__ coarse,    // [B, 3, NC]
    float* __restrict__ out)             // [B, 3, SOUT]
{
    const int b = blockIdx.x;
    const int t = threadIdx.x;
    const int wid = t >> 6;
    const int lane = t & 63;

    __shared__ float s_q[3];                  // broadcast query point
    __shared__ unsigned long long s_key[16];  // per-wave argmax partials
    __shared__ unsigned int s_last;           // winning point index m

    float x[KPT], y[KPT], z[KPT], md[KPT];

    const float* Pb = partial + (size_t)b * NP * 3;
    const float* Cb = coarse + (size_t)b * 3 * NC;

#pragma unroll
    for (int k = 0; k < KPT; ++k) {
        const int m = k * NTHR + t;
        if (k < KPART) {
            const int base = m * 3;
            x[k] = Pb[base + 0];
            y[k] = Pb[base + 1];
            z[k] = Pb[base + 2];
        } else {
            const int j = m - NP;
            x[k] = Cb[0 * NC + j];
            y[k] = Cb[1 * NC + j];
            z[k] = Cb[2 * NC + j];
        }
        md[k] = FLT_MAX;
    }

    float* outb = out + (size_t)b * 3 * SOUT;

    // First selected index is 0 (owned by thread 0, slot 0).
    if (t == 0) {
        s_q[0] = x[0]; s_q[1] = y[0]; s_q[2] = z[0];
        outb[0 * SOUT + 0] = x[0];
        outb[1 * SOUT + 0] = y[0];
        outb[2 * SOUT + 0] = z[0];
    }
    __syncthreads();

    for (int s = 0; s < SOUT - 1; ++s) {
        const float qx = s_q[0];
        const float qy = s_q[1];
        const float qz = s_q[2];

        // Update min_d for my 20 points; track local argmax (first-index ties:
        // strict > with ascending k keeps the earliest, m ascends with k).
        float bv = -1.0f;
        int bi = 0;
#pragma unroll
        for (int k = 0; k < KPT; ++k) {
            const float dx = __fsub_rn(x[k], qx);
            const float dy = __fsub_rn(y[k], qy);
            const float dz = __fsub_rn(z[k], qz);
            // Replicate LLVM's canonical FMA contraction of
            // (dx*dx + dy*dy) + dz*dz:  fma(dz,dz, fma(dx,dx, rn(dy*dy))).
            const float dy2 = __fmul_rn(dy, dy);
            const float tsum = __builtin_fmaf(dx, dx, dy2);
            const float d = __builtin_fmaf(dz, dz, tsum);
            const float nmd = fminf(md[k], d);
            md[k] = nmd;
            if (nmd > bv) { bv = nmd; bi = k; }
        }
        // Pack (value, index) into a u64 key: float bits are monotone for v>=0,
        // ~m makes equal values resolve to the smallest global index.
        const unsigned int mbest = (unsigned int)((bi << 10) | t);
        unsigned long long bk =
            ((unsigned long long)__float_as_uint(bv) << 32) |
            (unsigned long long)(~mbest);

        // Wave-level max-reduce of the key.
#pragma unroll
        for (int off = 32; off > 0; off >>= 1) {
            const unsigned long long o = shflxor64(bk, off);
            if (o > bk) bk = o;
        }
        if (lane == 0) s_key[wid] = bk;
        __syncthreads();

        // Cross-wave reduce on wave 0, lanes 0..15.
        if (wid == 0) {
            unsigned long long kk = (lane < 16) ? s_key[lane] : 0ULL;
#pragma unroll
            for (int off = 8; off > 0; off >>= 1) {
                const unsigned long long o = shflxor64(kk, off);
                if (o > kk) kk = o;
            }
            if (lane == 0) s_last = ~((unsigned int)kk);
        }
        __syncthreads();

        const unsigned int wm = s_last;
        // Owner thread broadcasts the winner's coords and writes the output
        // slot directly (fused gather).
        if ((wm & (NTHR - 1)) == (unsigned int)t) {
            const int kk = (int)(wm >> 10);
            float wx = 0.f, wy = 0.f, wz = 0.f;
#pragma unroll
            for (int k = 0; k < KPT; ++k) {
                if (k == kk) { wx = x[k]; wy = y[k]; wz = z[k]; }
            }
            s_q[0] = wx; s_q[1] = wy; s_q[2] = wz;
            const int slot = s + 1;
            outb[0 * SOUT + slot] = wx;
            outb[1 * SOUT + slot] = wy;
            outb[2 * SOUT + slot] = wz;
        }
        __syncthreads();
    }
}

extern "C" void kernel_launch(void* const* d_in, const int* in_sizes, int n_in,
                              void* d_out, int out_size, void* d_ws, size_t ws_size,
                              hipStream_t stream) {
    (void)in_sizes; (void)n_in; (void)d_ws; (void)ws_size; (void)out_size;
    const float* partial = (const float*)d_in[0];
    const float* coarse  = (const float*)d_in[1];
    float* out = (float*)d_out;
    fps_kernel<<<dim3(BATCH), dim3(NTHR), 0, stream>>>(partial, coarse, out);
}